// Round 12
// baseline (436.171 us; speedup 1.0000x reference)
//
#include <hip/hip_runtime.h>
#include <hip/hip_bf16.h>

#define LOG_2PI 1.8378770664093453f
#define R0 256        // rows resident in LDS triangle
#define GSTRIDE 512   // floats per global tail row
#define TRI_FLOATS 33280   // tribase(256)
#define CSTR 68            // corner LDS row stride (64 + 4 pad)
#define NT 256
#define SMEM_FLOATS (TRI_FLOATS + 512 + 512 + 512 + 16 + 8 + 64*CSTR)
#define SMEM_BYTES (SMEM_FLOATS * 4)   // 156768 <= 163840

// packed triangle: row r at [tribase(r)], 16B-aligned row starts
__device__ __forceinline__ int tribase(int r) {
    int m = r & 3;
    return r * (r + 1) / 2 + 6 * (r >> 2) + ((m * (7 - m)) >> 1);
}

// ---------------------------------------------------------------------------
// cov = A A^T (512x512) with A built on the fly from lt/logd.
// 136 lower-triangle 32x32 blocks, mirrored writes.
// A[i][k] = lt[i(i-1)/2+k] (k<i), exp(logd[i]) (k==i), 0 (k>i).
// ---------------------------------------------------------------------------
__global__ __launch_bounds__(256) void aat(const float* __restrict__ logd,
                                           const float* __restrict__ lt,
                                           float* __restrict__ C) {
    __shared__ float Ash[32][33];
    __shared__ float Bsh[32][33];
    int tx = threadIdx.x & 31, ty = threadIdx.x >> 5;
    int e = blockIdx.x;
    int bi = 0;
    while ((bi + 1) * (bi + 2) / 2 <= e) bi++;
    int bj = e - bi * (bi + 1) / 2;
    float acc[4] = {0.f, 0.f, 0.f, 0.f};
    for (int k0 = 0; k0 < 512; k0 += 32) {
        #pragma unroll
        for (int q = 0; q < 4; q++) {
            int rA = bi * 32 + ty + q * 8, kA = k0 + tx;
            float vA;
            if (kA < rA)       vA = lt[(rA * (rA - 1)) / 2 + kA];
            else if (kA == rA) vA = expf(logd[rA]);
            else               vA = 0.f;
            Ash[ty + q * 8][tx] = vA;
            int rB = bj * 32 + ty + q * 8;
            float vB;
            if (kA < rB)       vB = lt[(rB * (rB - 1)) / 2 + kA];
            else if (kA == rB) vB = expf(logd[rB]);
            else               vB = 0.f;
            Bsh[ty + q * 8][tx] = vB;
        }
        __syncthreads();
        for (int c = 0; c < 32; c++) {
            float bv = Bsh[tx][c];
            #pragma unroll
            for (int q = 0; q < 4; q++) acc[q] += Ash[ty + q * 8][c] * bv;
        }
        __syncthreads();
    }
    #pragma unroll
    for (int q = 0; q < 4; q++) {
        int i = bi * 32 + ty + q * 8, j = bj * 32 + tx;
        C[(size_t)i * 512 + j] = acc[q];
        if (bi != bj) C[(size_t)j * 512 + i] = acc[q];
    }
}

// ---------------------------------------------------------------------------
// Diag-block Cholesky + z-panel solve (lanes 0..31). rsqrt-based chains.
// ---------------------------------------------------------------------------
template <typename RPF>
__device__ __forceinline__ void diag_block(RPF rptr, float* zsh, float* dinvAll,
                                           float& llog, int j0, int nb, int n, int tid) {
    if (tid < 32) {
        int l = tid;
        int r = j0 + l;
        float a[32];
        float z = 0.f;
        if (r < n) {
            const float4* src = (const float4*)(rptr(r) + j0);
            #pragma unroll
            for (int q = 0; q < 8; q++) {
                float4 t = src[q];
                a[4*q+0] = t.x; a[4*q+1] = t.y; a[4*q+2] = t.z; a[4*q+3] = t.w;
            }
            z = zsh[r];
        } else {
            #pragma unroll
            for (int q = 0; q < 32; q++) a[q] = 0.f;
        }
        float dv = 0.f;
        #pragma unroll
        for (int k = 0; k < 32; k++) {
            if (k < nb) {
                float akk = __shfl(a[k], k, 64);
                float rin = rsqrtf(akk);
                float lkk = akk * rin;
                if (l == k) { dv = rin; llog += __logf(lkk); }
                a[k] = (l == k) ? lkk : a[k] * rin;
                #pragma unroll
                for (int j = k + 1; j < 32; j++) {
                    float ajk = __shfl(a[k], j, 64);
                    a[j] -= a[k] * ajk;
                }
            }
        }
        #pragma unroll
        for (int k = 0; k < 32; k++) {
            if (k < nb) {
                if (l == k) z *= dv;
                float zk = __shfl(z, k, 64);
                if (l > k) z -= a[k] * zk;
            }
        }
        dinvAll[j0 + l] = dv;
        if (l < nb) {
            zsh[r] = z;
            float* dst = rptr(r) + j0;
            #pragma unroll
            for (int c = 0; c < 32; c++)
                if (c <= l) dst[c] = a[c];
        }
    }
}

// ---------------------------------------------------------------------------
// Wave-level 32x32 syrk macro-pair: lanes form an 8x8 grid of 4x4 tiles.
// ---------------------------------------------------------------------------
__device__ __forceinline__ void syrk_macro32(float* T, int rbase0, int cbase0,
                                             int j0, int n0, int lane, bool diag) {
    int ty = lane >> 3, tx = lane & 7;
    int rbase = rbase0 + ty * 4, cbase = cbase0 + tx * 4;
    if (diag && cbase > rbase + 3) return;
    int ra[4], rb[4];
    #pragma unroll
    for (int a = 0; a < 4; a++) {
        ra[a] = tribase(min(rbase + a, n0 - 1)) + j0;
        rb[a] = tribase(min(cbase + a, n0 - 1)) + j0;
    }
    float acc[4][4];
    #pragma unroll
    for (int a = 0; a < 4; a++)
        #pragma unroll
        for (int c = 0; c < 4; c++) acc[a][c] = 0.f;
    #pragma unroll
    for (int q = 0; q < 8; q++) {
        float4 av[4], bv[4];
        #pragma unroll
        for (int a = 0; a < 4; a++) av[a] = *(const float4*)&T[ra[a] + 4 * q];
        #pragma unroll
        for (int c = 0; c < 4; c++) bv[c] = *(const float4*)&T[rb[c] + 4 * q];
        #pragma unroll
        for (int a = 0; a < 4; a++)
            #pragma unroll
            for (int c = 0; c < 4; c++)
                acc[a][c] += av[a].x*bv[c].x + av[a].y*bv[c].y +
                             av[a].z*bv[c].z + av[a].w*bv[c].w;
    }
    #pragma unroll
    for (int a = 0; a < 4; a++) {
        int r = rbase + a;
        if (r < n0) {
            float* trow = T + tribase(r);
            if (cbase + 3 <= r) {
                float4 v = *(const float4*)&trow[cbase];
                v.x -= acc[a][0]; v.y -= acc[a][1];
                v.z -= acc[a][2]; v.w -= acc[a][3];
                *(float4*)&trow[cbase] = v;
            } else {
                #pragma unroll
                for (int c = 0; c < 4; c++) {
                    int cl = cbase + c;
                    if (cl <= r) trow[cl] -= acc[a][c];
                }
            }
        }
    }
}

// ---------------------------------------------------------------------------
__global__ __launch_bounds__(NT) void chol_solve(
    const float* __restrict__ cov, const float* __restrict__ x,
    const float* __restrict__ mu, const int* __restrict__ mask,
    float* __restrict__ gtail_all, float* __restrict__ out) {

    extern __shared__ float smem[];
    float* T       = smem;                      // TRI_FLOATS
    float* zsh     = T + TRI_FLOATS;            // 512
    int*   oi      = (int*)(zsh + 512);         // 512
    float* dinvAll = (float*)(oi + 512);        // 512
    float* red     = dinvAll + 512;             // 16
    int*   csh     = (int*)(red + 16);          // 8: wsum[4] + nsh
    float* SBc     = (float*)(csh + 8);         // 64 * CSTR

    int b = blockIdx.x, tid = threadIdx.x;
    int lane = tid & 63, wv = tid >> 6;
    float* gtail = gtail_all + (size_t)b * 256 * GSTRIDE;

    // ---- inline compact: mask prefix-sum -> oi / zsh in LDS ----
    {
        int i0 = 2 * tid, i1 = 2 * tid + 1;
        int m0 = (mask[b * 512 + i0] != 0) ? 1 : 0;
        int m1 = (mask[b * 512 + i1] != 0) ? 1 : 0;
        int local = m0 + m1;
        int v = local;
        #pragma unroll
        for (int off = 1; off < 64; off <<= 1) {
            int u = __shfl_up(v, off, 64);
            if (lane >= off) v += u;
        }
        if (lane == 63) csh[wv] = v;
        __syncthreads();
        int woff = 0;
        for (int w = 0; w < wv; w++) woff += csh[w];
        int excl = woff + v - local;
        if (m0) { oi[excl] = i0; zsh[excl] = x[b * 512 + i0] - mu[i0]; }
        if (m1) { int p = excl + m0; oi[p] = i1; zsh[p] = x[b * 512 + i1] - mu[i1]; }
        if (tid == 0) csh[4] = csh[0] + csh[1] + csh[2] + csh[3];
        __syncthreads();
    }
    int n = csh[4]; if (n > 512) n = 512;
    if (n == 0) { if (tid == 0) out[b] = 0.f; return; }

    int n0 = (n < R0) ? n : R0;
    int ntail = n - n0;          // >0 only when n0 == 256

    // ---- gather triangle rows (LDS) + tail K21 rows (gtail) ----
    for (int r = wv; r < n0; r += 4) {
        const float* crow = cov + (size_t)oi[r] * 512;
        float* dst = T + tribase(r);
        #pragma unroll 4
        for (int j = lane; j <= r; j += 64) dst[j] = crow[oi[j]];
    }
    for (int r = n0 + wv; r < n; r += 4) {
        const float* crow = cov + (size_t)oi[r] * 512;
        float* dst = gtail + (size_t)(r - n0) * GSTRIDE;
        #pragma unroll 4
        for (int j = lane; j < n0; j += 64) dst[j] = crow[oi[j]];
    }
    __syncthreads();

    float llog = 0.f;

    // ================= main loop ==================
    for (int j0 = 0; j0 < n0; j0 += 32) {
        int nb = min(32, n0 - j0);
        diag_block([&](int r) { return T + tribase(r); },
                   zsh, dinvAll, llog, j0, nb, n0, tid);
        __syncthreads();

        int mL = n0 - j0 - 32; if (mL < 0) mL = 0;
        int mtot = mL + ntail;
        if (mtot == 0) continue;

        // ---- unified trsm: LDS rows + tail rows vs diag block j0 ----
        {
            float dvv[32];
            #pragma unroll
            for (int q = 0; q < 8; q++) {
                float4 t4 = *(const float4*)&dinvAll[j0 + 4 * q];
                dvv[4*q+0] = t4.x; dvv[4*q+1] = t4.y;
                dvv[4*q+2] = t4.z; dvv[4*q+3] = t4.w;
            }
            for (int idx = tid; idx < mtot; idx += NT) {
                int r; float* prow;
                if (idx < mL) { r = j0 + 32 + idx; prow = T + tribase(r) + j0; }
                else          { r = n0 + (idx - mL);
                                prow = gtail + (size_t)(idx - mL) * GSTRIDE + j0; }
                float p[32];
                #pragma unroll
                for (int q = 0; q < 8; q++) {
                    float4 t = *(const float4*)&prow[4 * q];
                    p[4*q+0] = t.x; p[4*q+1] = t.y; p[4*q+2] = t.z; p[4*q+3] = t.w;
                }
                #pragma unroll
                for (int j = 0; j < 32; j++) {
                    const float* dj = T + tribase(j0 + j) + j0;
                    float s0 = 0.f, s1 = 0.f, s2 = 0.f, s3 = 0.f;
                    int jf = j >> 2;
                    for (int q2 = 0; q2 < jf; q2++) {
                        float4 t = *(const float4*)&dj[q2 * 4];
                        s0 += p[q2*4+0]*t.x; s1 += p[q2*4+1]*t.y;
                        s2 += p[q2*4+2]*t.z; s3 += p[q2*4+3]*t.w;
                    }
                    float acc = p[j] - ((s0 + s1) + (s2 + s3));
                    for (int c = jf * 4; c < j; c++) acc -= p[c] * dj[c];
                    p[j] = acc * dvv[j];
                }
                float zu = 0.f;
                #pragma unroll
                for (int q = 0; q < 8; q++) {
                    *(float4*)&prow[4 * q] = make_float4(p[4*q], p[4*q+1], p[4*q+2], p[4*q+3]);
                    float4 zz = *(const float4*)&zsh[j0 + 4 * q];
                    zu += p[4*q]*zz.x + p[4*q+1]*zz.y + p[4*q+2]*zz.z + p[4*q+3]*zz.w;
                }
                zsh[r] -= zu;
            }
        }
        __syncthreads();

        // ---- syrk: wave-owned 32x32 macro-pairs (broadcast-friendly) ----
        if (mL > 0) {
            int nMac = (mL + 31) >> 5;
            int pairs = nMac * (nMac + 1) / 2;
            for (int e = wv; e < pairs; e += 4) {
                int MI = 0;
                while ((MI + 1) * (MI + 2) / 2 <= e) MI++;
                int MJ = e - MI * (MI + 1) / 2;
                syrk_macro32(T, j0 + 32 + MI * 32, j0 + 32 + MJ * 32,
                             j0, n0, lane, MI == MJ);
            }
        }

        // ---- tail-GEMM: wave-owned 32x32 macros (gtail rows x T cols) ----
        if (ntail > 0 && mL > 0) {
            int nRM = (ntail + 31) >> 5;
            int nCM = mL >> 5;
            int tot = nRM * nCM;
            int ty = lane >> 3, tx = lane & 7;
            for (int e = wv; e < tot; e += 4) {
                int MI = e / nCM, MJ = e % nCM;
                int r0 = MI * 32 + ty * 4;
                int c0 = j0 + 32 + MJ * 32 + tx * 4;
                int rb[4], tcb[4];
                #pragma unroll
                for (int a = 0; a < 4; a++) {
                    rb[a] = min(r0 + a, ntail - 1);
                    tcb[a] = tribase(min(c0 + a, n0 - 1)) + j0;
                }
                float acc[4][4];
                #pragma unroll
                for (int a = 0; a < 4; a++)
                    #pragma unroll
                    for (int c = 0; c < 4; c++) acc[a][c] = 0.f;
                #pragma unroll
                for (int q = 0; q < 8; q++) {
                    float4 av[4], bv[4];
                    #pragma unroll
                    for (int a = 0; a < 4; a++)
                        av[a] = *(const float4*)&gtail[(size_t)rb[a] * GSTRIDE + j0 + 4 * q];
                    #pragma unroll
                    for (int c = 0; c < 4; c++)
                        bv[c] = *(const float4*)&T[tcb[c] + 4 * q];
                    #pragma unroll
                    for (int a = 0; a < 4; a++)
                        #pragma unroll
                        for (int c = 0; c < 4; c++)
                            acc[a][c] += av[a].x*bv[c].x + av[a].y*bv[c].y +
                                         av[a].z*bv[c].z + av[a].w*bv[c].w;
                }
                #pragma unroll
                for (int a = 0; a < 4; a++) {
                    int r = r0 + a;
                    if (r < ntail) {
                        float* grow = gtail + (size_t)r * GSTRIDE;
                        float4 g4 = *(const float4*)&grow[c0];
                        g4.x -= acc[a][0]; g4.y -= acc[a][1];
                        g4.z -= acc[a][2]; g4.w -= acc[a][3];
                        *(float4*)&grow[c0] = g4;
                    }
                }
            }
        }
        __syncthreads();
    }

    // ================= corner groups (rows >= R0) =========================
    for (int gs2 = R0; gs2 < n; gs2 += 64) {
        int t1 = min(64, n - gs2);
        int g1 = gs2 - R0;

        // (A) extend W over previous corner groups' cols [R0..gs2)
        for (int cp = R0; cp < gs2; cp += 32) {
            if (tid < t1) {
                int r = gs2 + tid;
                float* row = gtail + (size_t)(r - R0) * GSTRIDE;
                const float* crow = cov + (size_t)oi[r] * 512;
                float zacc = 0.f;
                for (int j = 0; j < 32; j++) {
                    int jj = cp + j;
                    const float* Lrow = gtail + (size_t)(jj - R0) * GSTRIDE;
                    float s0 = 0.f, s1 = 0.f, s2 = 0.f, s3 = 0.f;
                    int jv = jj >> 2;
                    for (int c4 = 0; c4 < jv; c4++) {
                        float4 a4 = *(const float4*)&row[c4 * 4];
                        float4 b4 = *(const float4*)&Lrow[c4 * 4];
                        s0 += a4.x*b4.x; s1 += a4.y*b4.y;
                        s2 += a4.z*b4.z; s3 += a4.w*b4.w;
                    }
                    float acc = crow[oi[jj]] - ((s0 + s1) + (s2 + s3));
                    for (int c = jv * 4; c < jj; c++) acc -= row[c] * Lrow[c];
                    float wv2 = acc * dinvAll[jj];
                    row[jj] = wv2;
                    zacc += wv2 * zsh[jj];
                }
                zsh[r] -= zacc;
            }
            __syncthreads();
        }

        // (B) corner S = G22 - W W^T
        {
            int npair = t1 * (t1 + 1) / 2;
            for (int e = tid; e < npair; e += NT) {
                int ti = (int)((sqrtf(8.f * (float)e + 1.f) - 1.f) * 0.5f);
                while ((ti + 1) * (ti + 2) / 2 <= e) ti++;
                while (ti * (ti + 1) / 2 > e) ti--;
                int tj = e - ti * (ti + 1) / 2;
                const float* wa = gtail + (size_t)(g1 + ti) * GSTRIDE;
                const float* wb = gtail + (size_t)(g1 + tj) * GSTRIDE;
                float s0 = 0.f, s1 = 0.f, s2 = 0.f, s3 = 0.f;
                for (int k = 0; k < gs2; k += 4) {
                    float4 a4 = *(const float4*)&wa[k];
                    float4 b4 = *(const float4*)&wb[k];
                    s0 += a4.x*b4.x; s1 += a4.y*b4.y;
                    s2 += a4.z*b4.z; s3 += a4.w*b4.w;
                }
                SBc[ti * CSTR + tj] = cov[(size_t)oi[gs2 + ti] * 512 + oi[gs2 + tj]]
                                      - ((s0 + s1) + (s2 + s3));
            }
        }
        __syncthreads();

        // (C) factor corner (<= 64x64) in SBc
        auto crptr = [&](int r) { return SBc + (r - gs2) * CSTR - gs2; };
        diag_block(crptr, zsh, dinvAll, llog, gs2, min(32, t1), n, tid);
        __syncthreads();
        if (t1 > 32) {
            int t2 = t1 - 32;
            if (tid < t2) {
                int r = gs2 + 32 + tid;
                float* prow = SBc + (32 + tid) * CSTR;
                float p[32];
                #pragma unroll
                for (int q = 0; q < 8; q++) {
                    float4 t = *(const float4*)&prow[4 * q];
                    p[4*q+0] = t.x; p[4*q+1] = t.y; p[4*q+2] = t.z; p[4*q+3] = t.w;
                }
                #pragma unroll
                for (int j = 0; j < 32; j++) {
                    const float* dj = SBc + j * CSTR;
                    float s0 = 0.f, s1 = 0.f, s2 = 0.f, s3 = 0.f;
                    int jf = j >> 2;
                    for (int q2 = 0; q2 < jf; q2++) {
                        float4 t = *(const float4*)&dj[q2 * 4];
                        s0 += p[q2*4+0]*t.x; s1 += p[q2*4+1]*t.y;
                        s2 += p[q2*4+2]*t.z; s3 += p[q2*4+3]*t.w;
                    }
                    float acc = p[j] - ((s0 + s1) + (s2 + s3));
                    for (int c = jf * 4; c < j; c++) acc -= p[c] * dj[c];
                    p[j] = acc * dinvAll[gs2 + j];
                }
                float zu = 0.f;
                #pragma unroll
                for (int q = 0; q < 8; q++) {
                    *(float4*)&prow[4 * q] = make_float4(p[4*q], p[4*q+1], p[4*q+2], p[4*q+3]);
                    float4 zz = *(const float4*)&zsh[gs2 + 4 * q];
                    zu += p[4*q]*zz.x + p[4*q+1]*zz.y + p[4*q+2]*zz.z + p[4*q+3]*zz.w;
                }
                zsh[r] -= zu;
            }
            __syncthreads();
            int np2 = t2 * (t2 + 1) / 2;
            for (int e = tid; e < np2; e += NT) {
                int ti = (int)((sqrtf(8.f * (float)e + 1.f) - 1.f) * 0.5f);
                while ((ti + 1) * (ti + 2) / 2 <= e) ti++;
                while (ti * (ti + 1) / 2 > e) ti--;
                int tj = e - ti * (ti + 1) / 2;
                const float* wa = SBc + (32 + ti) * CSTR;
                const float* wb = SBc + (32 + tj) * CSTR;
                float s0 = 0.f, s1 = 0.f, s2 = 0.f, s3 = 0.f;
                #pragma unroll
                for (int q = 0; q < 8; q++) {
                    float4 a4 = *(const float4*)&wa[4 * q];
                    float4 b4 = *(const float4*)&wb[4 * q];
                    s0 += a4.x*b4.x; s1 += a4.y*b4.y;
                    s2 += a4.z*b4.z; s3 += a4.w*b4.w;
                }
                SBc[(32 + ti) * CSTR + 32 + tj] -= (s0 + s1) + (s2 + s3);
            }
            __syncthreads();
            diag_block(crptr, zsh, dinvAll, llog, gs2 + 32, min(32, t2), n, tid);
            __syncthreads();
        }
        // persist factored corner rows for later groups
        if (gs2 + 64 < n) {
            for (int e = tid; e < t1 * 64; e += NT) {
                int i = e >> 6, j = e & 63;
                if (j <= i && i < t1)
                    gtail[(size_t)(g1 + i) * GSTRIDE + gs2 + j] = SBc[i * CSTR + j];
            }
            __syncthreads();
        }
    }

    // ================= epilogue ==================
    float q = 0.f;
    for (int ii = tid; ii < n; ii += NT) { float zv = zsh[ii]; q += zv * zv; }
    #pragma unroll
    for (int off = 32; off; off >>= 1) {
        q    += __shfl_down(q, off, 64);
        llog += __shfl_down(llog, off, 64);
    }
    if (lane == 0) { red[wv] = q; red[8 + wv] = llog; }
    __syncthreads();
    if (tid == 0) {
        float qt = red[0] + red[1] + red[2] + red[3];
        float ls = red[8] + red[9] + red[10] + red[11];
        out[b] = 0.5f * (qt + 2.f * ls + (float)n * LOG_2PI);
    }
}

// ---------------------------------------------------------------------------
// ws: [0,1M) cov | [1M, ...) gtail (256 rows x 512 f32 per block)
// ---------------------------------------------------------------------------
extern "C" void kernel_launch(void* const* d_in, const int* in_sizes, int n_in,
                              void* d_out, int out_size, void* d_ws, size_t ws_size,
                              hipStream_t stream) {
    const float* x    = (const float*)d_in[0];
    const float* mu   = (const float*)d_in[1];
    const float* logd = (const float*)d_in[2];
    const float* lt   = (const float*)d_in[3];
    const int*   mask = (const int*)d_in[4];
    float* out = (float*)d_out;

    char* ws = (char*)d_ws;
    float* cov   = (float*)(ws);
    float* gtail = (float*)(ws + 1048576);

    (void)hipFuncSetAttribute((const void*)chol_solve,
                              hipFuncAttributeMaxDynamicSharedMemorySize,
                              SMEM_BYTES);

    aat<<<136, 256, 0, stream>>>(logd, lt, cov);
    chol_solve<<<256, NT, SMEM_BYTES, stream>>>(cov, x, mu, mask, gtail, out);
}

// Round 13
// 415.255 us; speedup vs baseline: 1.0504x; 1.0504x over previous
//
#include <hip/hip_runtime.h>
#include <hip/hip_bf16.h>

#define LOG_2PI 1.8378770664093453f
#define R0 256        // rows resident in LDS triangle
#define GSTRIDE 512   // floats per global tail row
#define TRI_FLOATS 33280   // tribase(256)
#define CSTR 68            // corner LDS row stride (64 + 4 pad)
#define NT 256
#define SMEM_FLOATS (TRI_FLOATS + 512 + 512 + 512 + 16 + 64*CSTR)
#define SMEM_BYTES (SMEM_FLOATS * 4)   // 156736 <= 163840

// packed triangle: row r at [tribase(r)], 16B-aligned row starts
__device__ __forceinline__ int tribase(int r) {
    int m = r & 3;
    return r * (r + 1) / 2 + 6 * (r >> 2) + ((m * (7 - m)) >> 1);
}

// ---------------------------------------------------------------------------
// Fused pre-chain, one launch:
//   blocks 0..255   : cov = A A^T tile (bi,bj), A built on the fly from lt/logd
//   blocks 256..511 : per-sample mask compaction
// ---------------------------------------------------------------------------
__global__ __launch_bounds__(256) void prep(const float* __restrict__ logd,
                                            const float* __restrict__ lt,
                                            const float* __restrict__ x,
                                            const float* __restrict__ mu,
                                            const int* __restrict__ mask,
                                            float* __restrict__ C,
                                            int* __restrict__ obs_idx,
                                            int* __restrict__ n_obs,
                                            float* __restrict__ rc) {
    __shared__ float Ash[32][33];
    __shared__ float Bsh[32][33];
    __shared__ int wsum[4];

    if (blockIdx.x < 256) {
        // ---- aat tile: full square grid, row-coalesced writes ----
        int tx = threadIdx.x & 31, ty = threadIdx.x >> 5;
        int bi = blockIdx.x >> 4, bj = blockIdx.x & 15;
        float acc[4] = {0.f, 0.f, 0.f, 0.f};
        for (int k0 = 0; k0 < 512; k0 += 32) {
            #pragma unroll
            for (int q = 0; q < 4; q++) {
                int kA = k0 + tx;
                int rA = bi * 32 + ty + q * 8;
                float vA;
                if (kA < rA)       vA = lt[(rA * (rA - 1)) / 2 + kA];
                else if (kA == rA) vA = expf(logd[rA]);
                else               vA = 0.f;
                Ash[ty + q * 8][tx] = vA;
                int rB = bj * 32 + ty + q * 8;
                float vB;
                if (kA < rB)       vB = lt[(rB * (rB - 1)) / 2 + kA];
                else if (kA == rB) vB = expf(logd[rB]);
                else               vB = 0.f;
                Bsh[ty + q * 8][tx] = vB;
            }
            __syncthreads();
            for (int c = 0; c < 32; c++) {
                float bv = Bsh[tx][c];
                #pragma unroll
                for (int q = 0; q < 4; q++) acc[q] += Ash[ty + q * 8][c] * bv;
            }
            __syncthreads();
        }
        #pragma unroll
        for (int q = 0; q < 4; q++)
            C[(size_t)(bi * 32 + ty + q * 8) * 512 + bj * 32 + tx] = acc[q];
    } else {
        // ---- compact for sample b ----
        int b = blockIdx.x - 256, t = threadIdx.x;
        int i0 = 2 * t, i1 = 2 * t + 1;
        int m0 = (mask[b * 512 + i0] != 0) ? 1 : 0;
        int m1 = (mask[b * 512 + i1] != 0) ? 1 : 0;
        int local = m0 + m1;
        int v = local;
        int lane = t & 63, wv = t >> 6;
        #pragma unroll
        for (int off = 1; off < 64; off <<= 1) {
            int u = __shfl_up(v, off, 64);
            if (lane >= off) v += u;
        }
        if (lane == 63) wsum[wv] = v;
        __syncthreads();
        int woff = 0;
        for (int w = 0; w < wv; w++) woff += wsum[w];
        int excl = woff + v - local;
        if (m0) { obs_idx[b * 512 + excl] = i0; rc[b * 512 + excl] = x[b * 512 + i0] - mu[i0]; }
        if (m1) { int p = excl + m0; obs_idx[b * 512 + p] = i1; rc[b * 512 + p] = x[b * 512 + i1] - mu[i1]; }
        if (t == 0) n_obs[b] = wsum[0] + wsum[1] + wsum[2] + wsum[3];
    }
}

// ---------------------------------------------------------------------------
// Diag-block Cholesky + z-panel solve (lanes 0..31). rsqrt-based chains.
// ---------------------------------------------------------------------------
template <typename RPF>
__device__ __forceinline__ void diag_block(RPF rptr, float* zsh, float* dinvAll,
                                           float& llog, int j0, int nb, int n, int tid) {
    if (tid < 32) {
        int l = tid;
        int r = j0 + l;
        float a[32];
        float z = 0.f;
        if (r < n) {
            const float4* src = (const float4*)(rptr(r) + j0);
            #pragma unroll
            for (int q = 0; q < 8; q++) {
                float4 t = src[q];
                a[4*q+0] = t.x; a[4*q+1] = t.y; a[4*q+2] = t.z; a[4*q+3] = t.w;
            }
            z = zsh[r];
        } else {
            #pragma unroll
            for (int q = 0; q < 32; q++) a[q] = 0.f;
        }
        float dv = 0.f;
        #pragma unroll
        for (int k = 0; k < 32; k++) {
            if (k < nb) {
                float akk = __shfl(a[k], k, 64);
                float rin = rsqrtf(akk);
                float lkk = akk * rin;
                if (l == k) { dv = rin; llog += __logf(lkk); }
                a[k] = (l == k) ? lkk : a[k] * rin;
                #pragma unroll
                for (int j = k + 1; j < 32; j++) {
                    float ajk = __shfl(a[k], j, 64);
                    a[j] -= a[k] * ajk;
                }
            }
        }
        #pragma unroll
        for (int k = 0; k < 32; k++) {
            if (k < nb) {
                if (l == k) z *= dv;
                float zk = __shfl(z, k, 64);
                if (l > k) z -= a[k] * zk;
            }
        }
        dinvAll[j0 + l] = dv;
        if (l < nb) {
            zsh[r] = z;
            float* dst = rptr(r) + j0;
            #pragma unroll
            for (int c = 0; c < 32; c++)
                if (c <= l) dst[c] = a[c];
        }
    }
}

// ---------------------------------------------------------------------------
// Wave-level 32x32 syrk macro-pair: lanes form an 8x8 grid of 4x4 tiles.
// ---------------------------------------------------------------------------
__device__ __forceinline__ void syrk_macro32(float* T, int rbase0, int cbase0,
                                             int j0, int n0, int lane, bool diag) {
    int ty = lane >> 3, tx = lane & 7;
    int rbase = rbase0 + ty * 4, cbase = cbase0 + tx * 4;
    if (diag && cbase > rbase + 3) return;
    int ra[4], rb[4];
    #pragma unroll
    for (int a = 0; a < 4; a++) {
        ra[a] = tribase(min(rbase + a, n0 - 1)) + j0;
        rb[a] = tribase(min(cbase + a, n0 - 1)) + j0;
    }
    float acc[4][4];
    #pragma unroll
    for (int a = 0; a < 4; a++)
        #pragma unroll
        for (int c = 0; c < 4; c++) acc[a][c] = 0.f;
    #pragma unroll
    for (int q = 0; q < 8; q++) {
        float4 av[4], bv[4];
        #pragma unroll
        for (int a = 0; a < 4; a++) av[a] = *(const float4*)&T[ra[a] + 4 * q];
        #pragma unroll
        for (int c = 0; c < 4; c++) bv[c] = *(const float4*)&T[rb[c] + 4 * q];
        #pragma unroll
        for (int a = 0; a < 4; a++)
            #pragma unroll
            for (int c = 0; c < 4; c++)
                acc[a][c] += av[a].x*bv[c].x + av[a].y*bv[c].y +
                             av[a].z*bv[c].z + av[a].w*bv[c].w;
    }
    #pragma unroll
    for (int a = 0; a < 4; a++) {
        int r = rbase + a;
        if (r < n0) {
            float* trow = T + tribase(r);
            if (cbase + 3 <= r) {
                float4 v = *(const float4*)&trow[cbase];
                v.x -= acc[a][0]; v.y -= acc[a][1];
                v.z -= acc[a][2]; v.w -= acc[a][3];
                *(float4*)&trow[cbase] = v;
            } else {
                #pragma unroll
                for (int c = 0; c < 4; c++) {
                    int cl = cbase + c;
                    if (cl <= r) trow[cl] -= acc[a][c];
                }
            }
        }
    }
}

// ---------------------------------------------------------------------------
__global__ __launch_bounds__(NT) void chol_solve(
    const float* __restrict__ cov, const float* __restrict__ rc,
    const int* __restrict__ obs_idx, const int* __restrict__ n_obs,
    float* __restrict__ gtail_all, float* __restrict__ out) {

    extern __shared__ float smem[];
    float* T       = smem;                      // TRI_FLOATS
    float* zsh     = T + TRI_FLOATS;            // 512
    int*   oi      = (int*)(zsh + 512);         // 512
    float* dinvAll = (float*)(oi + 512);        // 512
    float* red     = dinvAll + 512;             // 16
    float* SBc     = red + 16;                  // 64 * CSTR

    int b = blockIdx.x, tid = threadIdx.x;
    int lane = tid & 63, wv = tid >> 6;
    int n = n_obs[b]; if (n > 512) n = 512;
    float* gtail = gtail_all + (size_t)b * 256 * GSTRIDE;
    if (n == 0) { if (tid == 0) out[b] = 0.f; return; }

    for (int i = tid; i < n; i += NT) {
        oi[i] = obs_idx[b * 512 + i];
        zsh[i] = rc[b * 512 + i];
    }
    __syncthreads();

    int n0 = (n < R0) ? n : R0;
    int ntail = n - n0;          // >0 only when n0 == 256

    // ---- gather triangle rows (LDS) + tail K21 rows (gtail) ----
    for (int r = wv; r < n0; r += 4) {
        const float* crow = cov + (size_t)oi[r] * 512;
        float* dst = T + tribase(r);
        #pragma unroll 4
        for (int j = lane; j <= r; j += 64) dst[j] = crow[oi[j]];
    }
    for (int r = n0 + wv; r < n; r += 4) {
        const float* crow = cov + (size_t)oi[r] * 512;
        float* dst = gtail + (size_t)(r - n0) * GSTRIDE;
        #pragma unroll 4
        for (int j = lane; j < n0; j += 64) dst[j] = crow[oi[j]];
    }
    __syncthreads();

    float llog = 0.f;

    // ================= main loop ==================
    for (int j0 = 0; j0 < n0; j0 += 32) {
        int nb = min(32, n0 - j0);
        diag_block([&](int r) { return T + tribase(r); },
                   zsh, dinvAll, llog, j0, nb, n0, tid);
        __syncthreads();

        int mL = n0 - j0 - 32; if (mL < 0) mL = 0;
        int mtot = mL + ntail;
        if (mtot == 0) continue;

        // ---- unified trsm: LDS rows + tail rows vs diag block j0 ----
        {
            float dvv[32];
            #pragma unroll
            for (int q = 0; q < 8; q++) {
                float4 t4 = *(const float4*)&dinvAll[j0 + 4 * q];
                dvv[4*q+0] = t4.x; dvv[4*q+1] = t4.y;
                dvv[4*q+2] = t4.z; dvv[4*q+3] = t4.w;
            }
            for (int idx = tid; idx < mtot; idx += NT) {
                int r; float* prow;
                if (idx < mL) { r = j0 + 32 + idx; prow = T + tribase(r) + j0; }
                else          { r = n0 + (idx - mL);
                                prow = gtail + (size_t)(idx - mL) * GSTRIDE + j0; }
                float p[32];
                #pragma unroll
                for (int q = 0; q < 8; q++) {
                    float4 t = *(const float4*)&prow[4 * q];
                    p[4*q+0] = t.x; p[4*q+1] = t.y; p[4*q+2] = t.z; p[4*q+3] = t.w;
                }
                #pragma unroll
                for (int j = 0; j < 32; j++) {
                    const float* dj = T + tribase(j0 + j) + j0;
                    float s0 = 0.f, s1 = 0.f, s2 = 0.f, s3 = 0.f;
                    int jf = j >> 2;
                    for (int q2 = 0; q2 < jf; q2++) {
                        float4 t = *(const float4*)&dj[q2 * 4];
                        s0 += p[q2*4+0]*t.x; s1 += p[q2*4+1]*t.y;
                        s2 += p[q2*4+2]*t.z; s3 += p[q2*4+3]*t.w;
                    }
                    float acc = p[j] - ((s0 + s1) + (s2 + s3));
                    for (int c = jf * 4; c < j; c++) acc -= p[c] * dj[c];
                    p[j] = acc * dvv[j];
                }
                float zu = 0.f;
                #pragma unroll
                for (int q = 0; q < 8; q++) {
                    *(float4*)&prow[4 * q] = make_float4(p[4*q], p[4*q+1], p[4*q+2], p[4*q+3]);
                    float4 zz = *(const float4*)&zsh[j0 + 4 * q];
                    zu += p[4*q]*zz.x + p[4*q+1]*zz.y + p[4*q+2]*zz.z + p[4*q+3]*zz.w;
                }
                zsh[r] -= zu;
            }
        }
        __syncthreads();

        // ---- syrk: wave-owned 32x32 macro-pairs (broadcast-friendly) ----
        if (mL > 0) {
            int nMac = (mL + 31) >> 5;
            int pairs = nMac * (nMac + 1) / 2;
            for (int e = wv; e < pairs; e += 4) {
                int MI = 0;
                while ((MI + 1) * (MI + 2) / 2 <= e) MI++;
                int MJ = e - MI * (MI + 1) / 2;
                syrk_macro32(T, j0 + 32 + MI * 32, j0 + 32 + MJ * 32,
                             j0, n0, lane, MI == MJ);
            }
        }

        // ---- tail-GEMM: wave-owned 32x32 macros (gtail rows x T cols) ----
        if (ntail > 0 && mL > 0) {
            int nRM = (ntail + 31) >> 5;
            int nCM = mL >> 5;
            int tot = nRM * nCM;
            int ty = lane >> 3, tx = lane & 7;
            for (int e = wv; e < tot; e += 4) {
                int MI = e / nCM, MJ = e % nCM;
                int r0 = MI * 32 + ty * 4;
                int c0 = j0 + 32 + MJ * 32 + tx * 4;
                int rb[4], tcb[4];
                #pragma unroll
                for (int a = 0; a < 4; a++) {
                    rb[a] = min(r0 + a, ntail - 1);
                    tcb[a] = tribase(min(c0 + a, n0 - 1)) + j0;
                }
                float acc[4][4];
                #pragma unroll
                for (int a = 0; a < 4; a++)
                    #pragma unroll
                    for (int c = 0; c < 4; c++) acc[a][c] = 0.f;
                #pragma unroll
                for (int q = 0; q < 8; q++) {
                    float4 av[4], bv[4];
                    #pragma unroll
                    for (int a = 0; a < 4; a++)
                        av[a] = *(const float4*)&gtail[(size_t)rb[a] * GSTRIDE + j0 + 4 * q];
                    #pragma unroll
                    for (int c = 0; c < 4; c++)
                        bv[c] = *(const float4*)&T[tcb[c] + 4 * q];
                    #pragma unroll
                    for (int a = 0; a < 4; a++)
                        #pragma unroll
                        for (int c = 0; c < 4; c++)
                            acc[a][c] += av[a].x*bv[c].x + av[a].y*bv[c].y +
                                         av[a].z*bv[c].z + av[a].w*bv[c].w;
                }
                #pragma unroll
                for (int a = 0; a < 4; a++) {
                    int r = r0 + a;
                    if (r < ntail) {
                        float* grow = gtail + (size_t)r * GSTRIDE;
                        float4 g4 = *(const float4*)&grow[c0];
                        g4.x -= acc[a][0]; g4.y -= acc[a][1];
                        g4.z -= acc[a][2]; g4.w -= acc[a][3];
                        *(float4*)&grow[c0] = g4;
                    }
                }
            }
        }
        __syncthreads();
    }

    // ================= corner groups (rows >= R0) =========================
    for (int gs2 = R0; gs2 < n; gs2 += 64) {
        int t1 = min(64, n - gs2);
        int g1 = gs2 - R0;

        // (A) extend W over previous corner groups' cols [R0..gs2)
        for (int cp = R0; cp < gs2; cp += 32) {
            if (tid < t1) {
                int r = gs2 + tid;
                float* row = gtail + (size_t)(r - R0) * GSTRIDE;
                const float* crow = cov + (size_t)oi[r] * 512;
                float zacc = 0.f;
                for (int j = 0; j < 32; j++) {
                    int jj = cp + j;
                    const float* Lrow = gtail + (size_t)(jj - R0) * GSTRIDE;
                    float s0 = 0.f, s1 = 0.f, s2 = 0.f, s3 = 0.f;
                    int jv = jj >> 2;
                    for (int c4 = 0; c4 < jv; c4++) {
                        float4 a4 = *(const float4*)&row[c4 * 4];
                        float4 b4 = *(const float4*)&Lrow[c4 * 4];
                        s0 += a4.x*b4.x; s1 += a4.y*b4.y;
                        s2 += a4.z*b4.z; s3 += a4.w*b4.w;
                    }
                    float acc = crow[oi[jj]] - ((s0 + s1) + (s2 + s3));
                    for (int c = jv * 4; c < jj; c++) acc -= row[c] * Lrow[c];
                    float wv2 = acc * dinvAll[jj];
                    row[jj] = wv2;
                    zacc += wv2 * zsh[jj];
                }
                zsh[r] -= zacc;
            }
            __syncthreads();
        }

        // (B) corner S = G22 - W W^T
        {
            int npair = t1 * (t1 + 1) / 2;
            for (int e = tid; e < npair; e += NT) {
                int ti = (int)((sqrtf(8.f * (float)e + 1.f) - 1.f) * 0.5f);
                while ((ti + 1) * (ti + 2) / 2 <= e) ti++;
                while (ti * (ti + 1) / 2 > e) ti--;
                int tj = e - ti * (ti + 1) / 2;
                const float* wa = gtail + (size_t)(g1 + ti) * GSTRIDE;
                const float* wb = gtail + (size_t)(g1 + tj) * GSTRIDE;
                float s0 = 0.f, s1 = 0.f, s2 = 0.f, s3 = 0.f;
                for (int k = 0; k < gs2; k += 4) {
                    float4 a4 = *(const float4*)&wa[k];
                    float4 b4 = *(const float4*)&wb[k];
                    s0 += a4.x*b4.x; s1 += a4.y*b4.y;
                    s2 += a4.z*b4.z; s3 += a4.w*b4.w;
                }
                SBc[ti * CSTR + tj] = cov[(size_t)oi[gs2 + ti] * 512 + oi[gs2 + tj]]
                                      - ((s0 + s1) + (s2 + s3));
            }
        }
        __syncthreads();

        // (C) factor corner (<= 64x64) in SBc
        auto crptr = [&](int r) { return SBc + (r - gs2) * CSTR - gs2; };
        diag_block(crptr, zsh, dinvAll, llog, gs2, min(32, t1), n, tid);
        __syncthreads();
        if (t1 > 32) {
            int t2 = t1 - 32;
            if (tid < t2) {
                int r = gs2 + 32 + tid;
                float* prow = SBc + (32 + tid) * CSTR;
                float p[32];
                #pragma unroll
                for (int q = 0; q < 8; q++) {
                    float4 t = *(const float4*)&prow[4 * q];
                    p[4*q+0] = t.x; p[4*q+1] = t.y; p[4*q+2] = t.z; p[4*q+3] = t.w;
                }
                #pragma unroll
                for (int j = 0; j < 32; j++) {
                    const float* dj = SBc + j * CSTR;
                    float s0 = 0.f, s1 = 0.f, s2 = 0.f, s3 = 0.f;
                    int jf = j >> 2;
                    for (int q2 = 0; q2 < jf; q2++) {
                        float4 t = *(const float4*)&dj[q2 * 4];
                        s0 += p[q2*4+0]*t.x; s1 += p[q2*4+1]*t.y;
                        s2 += p[q2*4+2]*t.z; s3 += p[q2*4+3]*t.w;
                    }
                    float acc = p[j] - ((s0 + s1) + (s2 + s3));
                    for (int c = jf * 4; c < j; c++) acc -= p[c] * dj[c];
                    p[j] = acc * dinvAll[gs2 + j];
                }
                float zu = 0.f;
                #pragma unroll
                for (int q = 0; q < 8; q++) {
                    *(float4*)&prow[4 * q] = make_float4(p[4*q], p[4*q+1], p[4*q+2], p[4*q+3]);
                    float4 zz = *(const float4*)&zsh[gs2 + 4 * q];
                    zu += p[4*q]*zz.x + p[4*q+1]*zz.y + p[4*q+2]*zz.z + p[4*q+3]*zz.w;
                }
                zsh[r] -= zu;
            }
            __syncthreads();
            int np2 = t2 * (t2 + 1) / 2;
            for (int e = tid; e < np2; e += NT) {
                int ti = (int)((sqrtf(8.f * (float)e + 1.f) - 1.f) * 0.5f);
                while ((ti + 1) * (ti + 2) / 2 <= e) ti++;
                while (ti * (ti + 1) / 2 > e) ti--;
                int tj = e - ti * (ti + 1) / 2;
                const float* wa = SBc + (32 + ti) * CSTR;
                const float* wb = SBc + (32 + tj) * CSTR;
                float s0 = 0.f, s1 = 0.f, s2 = 0.f, s3 = 0.f;
                #pragma unroll
                for (int q = 0; q < 8; q++) {
                    float4 a4 = *(const float4*)&wa[4 * q];
                    float4 b4 = *(const float4*)&wb[4 * q];
                    s0 += a4.x*b4.x; s1 += a4.y*b4.y;
                    s2 += a4.z*b4.z; s3 += a4.w*b4.w;
                }
                SBc[(32 + ti) * CSTR + 32 + tj] -= (s0 + s1) + (s2 + s3);
            }
            __syncthreads();
            diag_block(crptr, zsh, dinvAll, llog, gs2 + 32, min(32, t2), n, tid);
            __syncthreads();
        }
        // persist factored corner rows for later groups
        if (gs2 + 64 < n) {
            for (int e = tid; e < t1 * 64; e += NT) {
                int i = e >> 6, j = e & 63;
                if (j <= i && i < t1)
                    gtail[(size_t)(g1 + i) * GSTRIDE + gs2 + j] = SBc[i * CSTR + j];
            }
            __syncthreads();
        }
    }

    // ================= epilogue ==================
    float q = 0.f;
    for (int ii = tid; ii < n; ii += NT) { float zv = zsh[ii]; q += zv * zv; }
    #pragma unroll
    for (int off = 32; off; off >>= 1) {
        q    += __shfl_down(q, off, 64);
        llog += __shfl_down(llog, off, 64);
    }
    if (lane == 0) { red[wv] = q; red[8 + wv] = llog; }
    __syncthreads();
    if (tid == 0) {
        float qt = red[0] + red[1] + red[2] + red[3];
        float ls = red[8] + red[9] + red[10] + red[11];
        out[b] = 0.5f * (qt + 2.f * ls + (float)n * LOG_2PI);
    }
}

// ---------------------------------------------------------------------------
// ws: [0,1M) cov | n_obs | obs_idx | rc | gtail (256 rows x 512 f32 per block)
// ---------------------------------------------------------------------------
extern "C" void kernel_launch(void* const* d_in, const int* in_sizes, int n_in,
                              void* d_out, int out_size, void* d_ws, size_t ws_size,
                              hipStream_t stream) {
    const float* x    = (const float*)d_in[0];
    const float* mu   = (const float*)d_in[1];
    const float* logd = (const float*)d_in[2];
    const float* lt   = (const float*)d_in[3];
    const int*   mask = (const int*)d_in[4];
    float* out = (float*)d_out;

    char* ws = (char*)d_ws;
    float* cov     = (float*)(ws);
    int*   n_obs   = (int*)  (ws + 1048576);
    int*   obs_idx = (int*)  (ws + 1049600);
    float* rc      = (float*)(ws + 1573888);
    float* gtail   = (float*)(ws + 2098176);

    (void)hipFuncSetAttribute((const void*)chol_solve,
                              hipFuncAttributeMaxDynamicSharedMemorySize,
                              SMEM_BYTES);

    prep<<<512, 256, 0, stream>>>(logd, lt, x, mu, mask, cov, obs_idx, n_obs, rc);
    chol_solve<<<256, NT, SMEM_BYTES, stream>>>(cov, rc, obs_idx, n_obs, gtail, out);
}

// Round 14
// 398.615 us; speedup vs baseline: 1.0942x; 1.0417x over previous
//
#include <hip/hip_runtime.h>
#include <hip/hip_bf16.h>

#define LOG_2PI 1.8378770664093453f
#define R0 256        // rows resident in LDS triangle
#define GSTRIDE 512   // floats per global tail row
#define TRI_FLOATS 33280   // tribase(256)
#define CSTR 68            // corner LDS row stride (64 + 4 pad)
#define NT 256
#define SMEM_FLOATS (TRI_FLOATS + 512 + 512 + 512 + 16 + 64*CSTR)
#define SMEM_BYTES (SMEM_FLOATS * 4)   // 156736 <= 163840

// packed triangle: row r at [tribase(r)], 16B-aligned row starts
__device__ __forceinline__ int tribase(int r) {
    int m = r & 3;
    return r * (r + 1) / 2 + 6 * (r >> 2) + ((m * (7 - m)) >> 1);
}

// ---------------------------------------------------------------------------
// Fused build_A + compact (independent block ranges, one launch):
//   blocks 0..1023    : A[i][j] from lt/logd (idx = blk*256+tid)
//   blocks 1024..1279 : per-sample mask compaction
// ---------------------------------------------------------------------------
__global__ __launch_bounds__(256) void prep2(const float* __restrict__ logd,
                                             const float* __restrict__ lt,
                                             const float* __restrict__ x,
                                             const float* __restrict__ mu,
                                             const int* __restrict__ mask,
                                             float* __restrict__ A,
                                             int* __restrict__ obs_idx,
                                             int* __restrict__ n_obs,
                                             float* __restrict__ rc) {
    if (blockIdx.x < 1024) {
        int idx = blockIdx.x * 256 + threadIdx.x;
        int i = idx >> 9, j = idx & 511;
        float v;
        if (j < i)       v = lt[(i * (i - 1)) / 2 + j];
        else if (j == i) v = expf(logd[i]);
        else             v = 0.f;
        A[idx] = v;
    } else {
        __shared__ int wsum[4];
        int b = blockIdx.x - 1024, t = threadIdx.x;
        int i0 = 2 * t, i1 = 2 * t + 1;
        int m0 = (mask[b * 512 + i0] != 0) ? 1 : 0;
        int m1 = (mask[b * 512 + i1] != 0) ? 1 : 0;
        int local = m0 + m1;
        int v = local;
        int lane = t & 63, wv = t >> 6;
        #pragma unroll
        for (int off = 1; off < 64; off <<= 1) {
            int u = __shfl_up(v, off, 64);
            if (lane >= off) v += u;
        }
        if (lane == 63) wsum[wv] = v;
        __syncthreads();
        int woff = 0;
        for (int w = 0; w < wv; w++) woff += wsum[w];
        int excl = woff + v - local;
        if (m0) { obs_idx[b * 512 + excl] = i0; rc[b * 512 + excl] = x[b * 512 + i0] - mu[i0]; }
        if (m1) { int p = excl + m0; obs_idx[b * 512 + p] = i1; rc[b * 512 + p] = x[b * 512 + i1] - mu[i1]; }
        if (t == 0) n_obs[b] = wsum[0] + wsum[1] + wsum[2] + wsum[3];
    }
}

// cov = A A^T (512x512), 32x32 tiles, 256 blocks (R11's proven form).
__global__ __launch_bounds__(256) void aat(const float* __restrict__ A,
                                           float* __restrict__ C) {
    __shared__ float Ash[32][33];
    __shared__ float Bsh[32][33];
    int tx = threadIdx.x & 31, ty = threadIdx.x >> 5;
    int bi = blockIdx.y, bj = blockIdx.x;
    float acc[4] = {0.f, 0.f, 0.f, 0.f};
    for (int k0 = 0; k0 < 512; k0 += 32) {
        #pragma unroll
        for (int q = 0; q < 4; q++) {
            int r = ty + q * 8;
            Ash[r][tx] = A[(bi * 32 + r) * 512 + k0 + tx];
            Bsh[r][tx] = A[(bj * 32 + r) * 512 + k0 + tx];
        }
        __syncthreads();
        for (int c = 0; c < 32; c++) {
            float bv = Bsh[tx][c];
            #pragma unroll
            for (int q = 0; q < 4; q++) acc[q] += Ash[ty + q * 8][c] * bv;
        }
        __syncthreads();
    }
    #pragma unroll
    for (int q = 0; q < 4; q++)
        C[(bi * 32 + ty + q * 8) * 512 + bj * 32 + tx] = acc[q];
}

// ---------------------------------------------------------------------------
// Diag-block Cholesky + z-panel solve (lanes 0..31). rsqrt-based chains.
// ---------------------------------------------------------------------------
template <typename RPF>
__device__ __forceinline__ void diag_block(RPF rptr, float* zsh, float* dinvAll,
                                           float& llog, int j0, int nb, int n, int tid) {
    if (tid < 32) {
        int l = tid;
        int r = j0 + l;
        float a[32];
        float z = 0.f;
        if (r < n) {
            const float4* src = (const float4*)(rptr(r) + j0);
            #pragma unroll
            for (int q = 0; q < 8; q++) {
                float4 t = src[q];
                a[4*q+0] = t.x; a[4*q+1] = t.y; a[4*q+2] = t.z; a[4*q+3] = t.w;
            }
            z = zsh[r];
        } else {
            #pragma unroll
            for (int q = 0; q < 32; q++) a[q] = 0.f;
        }
        float dv = 0.f;
        #pragma unroll
        for (int k = 0; k < 32; k++) {
            if (k < nb) {
                float akk = __shfl(a[k], k, 64);
                float rin = rsqrtf(akk);
                float lkk = akk * rin;
                if (l == k) { dv = rin; llog += __logf(lkk); }
                a[k] = (l == k) ? lkk : a[k] * rin;
                #pragma unroll
                for (int j = k + 1; j < 32; j++) {
                    float ajk = __shfl(a[k], j, 64);
                    a[j] -= a[k] * ajk;
                }
            }
        }
        #pragma unroll
        for (int k = 0; k < 32; k++) {
            if (k < nb) {
                if (l == k) z *= dv;
                float zk = __shfl(z, k, 64);
                if (l > k) z -= a[k] * zk;
            }
        }
        dinvAll[j0 + l] = dv;
        if (l < nb) {
            zsh[r] = z;
            float* dst = rptr(r) + j0;
            #pragma unroll
            for (int c = 0; c < 32; c++)
                if (c <= l) dst[c] = a[c];
        }
    }
}

// ---------------------------------------------------------------------------
// Wave-level 32x32 syrk macro-pair: lanes form an 8x8 grid of 4x4 tiles.
// ---------------------------------------------------------------------------
__device__ __forceinline__ void syrk_macro32(float* T, int rbase0, int cbase0,
                                             int j0, int n0, int lane, bool diag) {
    int ty = lane >> 3, tx = lane & 7;
    int rbase = rbase0 + ty * 4, cbase = cbase0 + tx * 4;
    if (diag && cbase > rbase + 3) return;
    int ra[4], rb[4];
    #pragma unroll
    for (int a = 0; a < 4; a++) {
        ra[a] = tribase(min(rbase + a, n0 - 1)) + j0;
        rb[a] = tribase(min(cbase + a, n0 - 1)) + j0;
    }
    float acc[4][4];
    #pragma unroll
    for (int a = 0; a < 4; a++)
        #pragma unroll
        for (int c = 0; c < 4; c++) acc[a][c] = 0.f;
    #pragma unroll
    for (int q = 0; q < 8; q++) {
        float4 av[4], bv[4];
        #pragma unroll
        for (int a = 0; a < 4; a++) av[a] = *(const float4*)&T[ra[a] + 4 * q];
        #pragma unroll
        for (int c = 0; c < 4; c++) bv[c] = *(const float4*)&T[rb[c] + 4 * q];
        #pragma unroll
        for (int a = 0; a < 4; a++)
            #pragma unroll
            for (int c = 0; c < 4; c++)
                acc[a][c] += av[a].x*bv[c].x + av[a].y*bv[c].y +
                             av[a].z*bv[c].z + av[a].w*bv[c].w;
    }
    #pragma unroll
    for (int a = 0; a < 4; a++) {
        int r = rbase + a;
        if (r < n0) {
            float* trow = T + tribase(r);
            if (cbase + 3 <= r) {
                float4 v = *(const float4*)&trow[cbase];
                v.x -= acc[a][0]; v.y -= acc[a][1];
                v.z -= acc[a][2]; v.w -= acc[a][3];
                *(float4*)&trow[cbase] = v;
            } else {
                #pragma unroll
                for (int c = 0; c < 4; c++) {
                    int cl = cbase + c;
                    if (cl <= r) trow[cl] -= acc[a][c];
                }
            }
        }
    }
}

// ---------------------------------------------------------------------------
__global__ __launch_bounds__(NT) void chol_solve(
    const float* __restrict__ cov, const float* __restrict__ rc,
    const int* __restrict__ obs_idx, const int* __restrict__ n_obs,
    float* __restrict__ gtail_all, float* __restrict__ out) {

    extern __shared__ float smem[];
    float* T       = smem;                      // TRI_FLOATS
    float* zsh     = T + TRI_FLOATS;            // 512
    int*   oi      = (int*)(zsh + 512);         // 512
    float* dinvAll = (float*)(oi + 512);        // 512
    float* red     = dinvAll + 512;             // 16
    float* SBc     = red + 16;                  // 64 * CSTR

    int b = blockIdx.x, tid = threadIdx.x;
    int lane = tid & 63, wv = tid >> 6;
    int n = n_obs[b]; if (n > 512) n = 512;
    float* gtail = gtail_all + (size_t)b * 256 * GSTRIDE;
    if (n == 0) { if (tid == 0) out[b] = 0.f; return; }

    for (int i = tid; i < n; i += NT) {
        oi[i] = obs_idx[b * 512 + i];
        zsh[i] = rc[b * 512 + i];
    }
    __syncthreads();

    int n0 = (n < R0) ? n : R0;
    int ntail = n - n0;          // >0 only when n0 == 256

    // ---- gather triangle rows (LDS) + tail K21 rows (gtail) ----
    for (int r = wv; r < n0; r += 4) {
        const float* crow = cov + (size_t)oi[r] * 512;
        float* dst = T + tribase(r);
        #pragma unroll 4
        for (int j = lane; j <= r; j += 64) dst[j] = crow[oi[j]];
    }
    for (int r = n0 + wv; r < n; r += 4) {
        const float* crow = cov + (size_t)oi[r] * 512;
        float* dst = gtail + (size_t)(r - n0) * GSTRIDE;
        #pragma unroll 4
        for (int j = lane; j < n0; j += 64) dst[j] = crow[oi[j]];
    }
    __syncthreads();

    float llog = 0.f;

    // ================= main loop ==================
    for (int j0 = 0; j0 < n0; j0 += 32) {
        int nb = min(32, n0 - j0);
        diag_block([&](int r) { return T + tribase(r); },
                   zsh, dinvAll, llog, j0, nb, n0, tid);
        __syncthreads();

        int mL = n0 - j0 - 32; if (mL < 0) mL = 0;
        int mtot = mL + ntail;
        if (mtot == 0) continue;

        // ---- unified trsm: LDS rows + tail rows vs diag block j0 ----
        {
            float dvv[32];
            #pragma unroll
            for (int q = 0; q < 8; q++) {
                float4 t4 = *(const float4*)&dinvAll[j0 + 4 * q];
                dvv[4*q+0] = t4.x; dvv[4*q+1] = t4.y;
                dvv[4*q+2] = t4.z; dvv[4*q+3] = t4.w;
            }
            for (int idx = tid; idx < mtot; idx += NT) {
                int r; float* prow;
                if (idx < mL) { r = j0 + 32 + idx; prow = T + tribase(r) + j0; }
                else          { r = n0 + (idx - mL);
                                prow = gtail + (size_t)(idx - mL) * GSTRIDE + j0; }
                float p[32];
                #pragma unroll
                for (int q = 0; q < 8; q++) {
                    float4 t = *(const float4*)&prow[4 * q];
                    p[4*q+0] = t.x; p[4*q+1] = t.y; p[4*q+2] = t.z; p[4*q+3] = t.w;
                }
                #pragma unroll
                for (int j = 0; j < 32; j++) {
                    const float* dj = T + tribase(j0 + j) + j0;
                    float s0 = 0.f, s1 = 0.f, s2 = 0.f, s3 = 0.f;
                    int jf = j >> 2;
                    for (int q2 = 0; q2 < jf; q2++) {
                        float4 t = *(const float4*)&dj[q2 * 4];
                        s0 += p[q2*4+0]*t.x; s1 += p[q2*4+1]*t.y;
                        s2 += p[q2*4+2]*t.z; s3 += p[q2*4+3]*t.w;
                    }
                    float acc = p[j] - ((s0 + s1) + (s2 + s3));
                    for (int c = jf * 4; c < j; c++) acc -= p[c] * dj[c];
                    p[j] = acc * dvv[j];
                }
                float zu = 0.f;
                #pragma unroll
                for (int q = 0; q < 8; q++) {
                    *(float4*)&prow[4 * q] = make_float4(p[4*q], p[4*q+1], p[4*q+2], p[4*q+3]);
                    float4 zz = *(const float4*)&zsh[j0 + 4 * q];
                    zu += p[4*q]*zz.x + p[4*q+1]*zz.y + p[4*q+2]*zz.z + p[4*q+3]*zz.w;
                }
                zsh[r] -= zu;
            }
        }
        __syncthreads();

        // ---- syrk: wave-owned 32x32 macro-pairs (broadcast-friendly) ----
        if (mL > 0) {
            int nMac = (mL + 31) >> 5;
            int pairs = nMac * (nMac + 1) / 2;
            for (int e = wv; e < pairs; e += 4) {
                int MI = 0;
                while ((MI + 1) * (MI + 2) / 2 <= e) MI++;
                int MJ = e - MI * (MI + 1) / 2;
                syrk_macro32(T, j0 + 32 + MI * 32, j0 + 32 + MJ * 32,
                             j0, n0, lane, MI == MJ);
            }
        }

        // ---- tail-GEMM: wave-owned 32x32 macros (gtail rows x T cols) ----
        if (ntail > 0 && mL > 0) {
            int nRM = (ntail + 31) >> 5;
            int nCM = mL >> 5;
            int tot = nRM * nCM;
            int ty = lane >> 3, tx = lane & 7;
            for (int e = wv; e < tot; e += 4) {
                int MI = e / nCM, MJ = e % nCM;
                int r0 = MI * 32 + ty * 4;
                int c0 = j0 + 32 + MJ * 32 + tx * 4;
                int rb[4], tcb[4];
                #pragma unroll
                for (int a = 0; a < 4; a++) {
                    rb[a] = min(r0 + a, ntail - 1);
                    tcb[a] = tribase(min(c0 + a, n0 - 1)) + j0;
                }
                float acc[4][4];
                #pragma unroll
                for (int a = 0; a < 4; a++)
                    #pragma unroll
                    for (int c = 0; c < 4; c++) acc[a][c] = 0.f;
                #pragma unroll
                for (int q = 0; q < 8; q++) {
                    float4 av[4], bv[4];
                    #pragma unroll
                    for (int a = 0; a < 4; a++)
                        av[a] = *(const float4*)&gtail[(size_t)rb[a] * GSTRIDE + j0 + 4 * q];
                    #pragma unroll
                    for (int c = 0; c < 4; c++)
                        bv[c] = *(const float4*)&T[tcb[c] + 4 * q];
                    #pragma unroll
                    for (int a = 0; a < 4; a++)
                        #pragma unroll
                        for (int c = 0; c < 4; c++)
                            acc[a][c] += av[a].x*bv[c].x + av[a].y*bv[c].y +
                                         av[a].z*bv[c].z + av[a].w*bv[c].w;
                }
                #pragma unroll
                for (int a = 0; a < 4; a++) {
                    int r = r0 + a;
                    if (r < ntail) {
                        float* grow = gtail + (size_t)r * GSTRIDE;
                        float4 g4 = *(const float4*)&grow[c0];
                        g4.x -= acc[a][0]; g4.y -= acc[a][1];
                        g4.z -= acc[a][2]; g4.w -= acc[a][3];
                        *(float4*)&grow[c0] = g4;
                    }
                }
            }
        }
        __syncthreads();
    }

    // ================= corner groups (rows >= R0) =========================
    for (int gs2 = R0; gs2 < n; gs2 += 64) {
        int t1 = min(64, n - gs2);
        int g1 = gs2 - R0;

        // (A) extend W over previous corner groups' cols [R0..gs2)
        for (int cp = R0; cp < gs2; cp += 32) {
            if (tid < t1) {
                int r = gs2 + tid;
                float* row = gtail + (size_t)(r - R0) * GSTRIDE;
                const float* crow = cov + (size_t)oi[r] * 512;
                float zacc = 0.f;
                for (int j = 0; j < 32; j++) {
                    int jj = cp + j;
                    const float* Lrow = gtail + (size_t)(jj - R0) * GSTRIDE;
                    float s0 = 0.f, s1 = 0.f, s2 = 0.f, s3 = 0.f;
                    int jv = jj >> 2;
                    for (int c4 = 0; c4 < jv; c4++) {
                        float4 a4 = *(const float4*)&row[c4 * 4];
                        float4 b4 = *(const float4*)&Lrow[c4 * 4];
                        s0 += a4.x*b4.x; s1 += a4.y*b4.y;
                        s2 += a4.z*b4.z; s3 += a4.w*b4.w;
                    }
                    float acc = crow[oi[jj]] - ((s0 + s1) + (s2 + s3));
                    for (int c = jv * 4; c < jj; c++) acc -= row[c] * Lrow[c];
                    float wv2 = acc * dinvAll[jj];
                    row[jj] = wv2;
                    zacc += wv2 * zsh[jj];
                }
                zsh[r] -= zacc;
            }
            __syncthreads();
        }

        // (B) corner S = G22 - W W^T
        {
            int npair = t1 * (t1 + 1) / 2;
            for (int e = tid; e < npair; e += NT) {
                int ti = (int)((sqrtf(8.f * (float)e + 1.f) - 1.f) * 0.5f);
                while ((ti + 1) * (ti + 2) / 2 <= e) ti++;
                while (ti * (ti + 1) / 2 > e) ti--;
                int tj = e - ti * (ti + 1) / 2;
                const float* wa = gtail + (size_t)(g1 + ti) * GSTRIDE;
                const float* wb = gtail + (size_t)(g1 + tj) * GSTRIDE;
                float s0 = 0.f, s1 = 0.f, s2 = 0.f, s3 = 0.f;
                for (int k = 0; k < gs2; k += 4) {
                    float4 a4 = *(const float4*)&wa[k];
                    float4 b4 = *(const float4*)&wb[k];
                    s0 += a4.x*b4.x; s1 += a4.y*b4.y;
                    s2 += a4.z*b4.z; s3 += a4.w*b4.w;
                }
                SBc[ti * CSTR + tj] = cov[(size_t)oi[gs2 + ti] * 512 + oi[gs2 + tj]]
                                      - ((s0 + s1) + (s2 + s3));
            }
        }
        __syncthreads();

        // (C) factor corner (<= 64x64) in SBc
        auto crptr = [&](int r) { return SBc + (r - gs2) * CSTR - gs2; };
        diag_block(crptr, zsh, dinvAll, llog, gs2, min(32, t1), n, tid);
        __syncthreads();
        if (t1 > 32) {
            int t2 = t1 - 32;
            if (tid < t2) {
                int r = gs2 + 32 + tid;
                float* prow = SBc + (32 + tid) * CSTR;
                float p[32];
                #pragma unroll
                for (int q = 0; q < 8; q++) {
                    float4 t = *(const float4*)&prow[4 * q];
                    p[4*q+0] = t.x; p[4*q+1] = t.y; p[4*q+2] = t.z; p[4*q+3] = t.w;
                }
                #pragma unroll
                for (int j = 0; j < 32; j++) {
                    const float* dj = SBc + j * CSTR;
                    float s0 = 0.f, s1 = 0.f, s2 = 0.f, s3 = 0.f;
                    int jf = j >> 2;
                    for (int q2 = 0; q2 < jf; q2++) {
                        float4 t = *(const float4*)&dj[q2 * 4];
                        s0 += p[q2*4+0]*t.x; s1 += p[q2*4+1]*t.y;
                        s2 += p[q2*4+2]*t.z; s3 += p[q2*4+3]*t.w;
                    }
                    float acc = p[j] - ((s0 + s1) + (s2 + s3));
                    for (int c = jf * 4; c < j; c++) acc -= p[c] * dj[c];
                    p[j] = acc * dinvAll[gs2 + j];
                }
                float zu = 0.f;
                #pragma unroll
                for (int q = 0; q < 8; q++) {
                    *(float4*)&prow[4 * q] = make_float4(p[4*q], p[4*q+1], p[4*q+2], p[4*q+3]);
                    float4 zz = *(const float4*)&zsh[gs2 + 4 * q];
                    zu += p[4*q]*zz.x + p[4*q+1]*zz.y + p[4*q+2]*zz.z + p[4*q+3]*zz.w;
                }
                zsh[r] -= zu;
            }
            __syncthreads();
            int np2 = t2 * (t2 + 1) / 2;
            for (int e = tid; e < np2; e += NT) {
                int ti = (int)((sqrtf(8.f * (float)e + 1.f) - 1.f) * 0.5f);
                while ((ti + 1) * (ti + 2) / 2 <= e) ti++;
                while (ti * (ti + 1) / 2 > e) ti--;
                int tj = e - ti * (ti + 1) / 2;
                const float* wa = SBc + (32 + ti) * CSTR;
                const float* wb = SBc + (32 + tj) * CSTR;
                float s0 = 0.f, s1 = 0.f, s2 = 0.f, s3 = 0.f;
                #pragma unroll
                for (int q = 0; q < 8; q++) {
                    float4 a4 = *(const float4*)&wa[4 * q];
                    float4 b4 = *(const float4*)&wb[4 * q];
                    s0 += a4.x*b4.x; s1 += a4.y*b4.y;
                    s2 += a4.z*b4.z; s3 += a4.w*b4.w;
                }
                SBc[(32 + ti) * CSTR + 32 + tj] -= (s0 + s1) + (s2 + s3);
            }
            __syncthreads();
            diag_block(crptr, zsh, dinvAll, llog, gs2 + 32, min(32, t2), n, tid);
            __syncthreads();
        }
        // persist factored corner rows for later groups
        if (gs2 + 64 < n) {
            for (int e = tid; e < t1 * 64; e += NT) {
                int i = e >> 6, j = e & 63;
                if (j <= i && i < t1)
                    gtail[(size_t)(g1 + i) * GSTRIDE + gs2 + j] = SBc[i * CSTR + j];
            }
            __syncthreads();
        }
    }

    // ================= epilogue ==================
    float q = 0.f;
    for (int ii = tid; ii < n; ii += NT) { float zv = zsh[ii]; q += zv * zv; }
    #pragma unroll
    for (int off = 32; off; off >>= 1) {
        q    += __shfl_down(q, off, 64);
        llog += __shfl_down(llog, off, 64);
    }
    if (lane == 0) { red[wv] = q; red[8 + wv] = llog; }
    __syncthreads();
    if (tid == 0) {
        float qt = red[0] + red[1] + red[2] + red[3];
        float ls = red[8] + red[9] + red[10] + red[11];
        out[b] = 0.5f * (qt + 2.f * ls + (float)n * LOG_2PI);
    }
}

// ---------------------------------------------------------------------------
// ws: [0,1M) cov | [1M,2M) A | n_obs | obs_idx | rc | gtail
// ---------------------------------------------------------------------------
extern "C" void kernel_launch(void* const* d_in, const int* in_sizes, int n_in,
                              void* d_out, int out_size, void* d_ws, size_t ws_size,
                              hipStream_t stream) {
    const float* x    = (const float*)d_in[0];
    const float* mu   = (const float*)d_in[1];
    const float* logd = (const float*)d_in[2];
    const float* lt   = (const float*)d_in[3];
    const int*   mask = (const int*)d_in[4];
    float* out = (float*)d_out;

    char* ws = (char*)d_ws;
    float* cov     = (float*)(ws);
    float* A       = (float*)(ws + 1048576);
    int*   n_obs   = (int*)  (ws + 2097152);
    int*   obs_idx = (int*)  (ws + 2098176);
    float* rc      = (float*)(ws + 2622464);
    float* gtail   = (float*)(ws + 3146752);

    (void)hipFuncSetAttribute((const void*)chol_solve,
                              hipFuncAttributeMaxDynamicSharedMemorySize,
                              SMEM_BYTES);

    prep2<<<1280, 256, 0, stream>>>(logd, lt, x, mu, mask, A, obs_idx, n_obs, rc);
    dim3 g(16, 16);
    aat<<<g, 256, 0, stream>>>(A, cov);
    chol_solve<<<256, NT, SMEM_BYTES, stream>>>(cov, rc, obs_idx, n_obs, gtail, out);
}